// Round 4
// baseline (344.373 us; speedup 1.0000x reference)
//
#include <hip/hip_runtime.h>
#include <stdint.h>

// out[8192,4096] = x[8192,1024] @ W[4096,1024]^T + bias (all fp32; float_quantize
// exp=8/man=23 is an identity). Split-bf16: hi*hi + lo*hi + hi*lo, fp32 MFMA acc.
// Structure: 32x32x16 MFMA; A (per-wave-exclusive) direct global->reg from a
// fragment-contiguous packed layout; B via global_load_lds into a 32KB dbuf.
#define MM 8192
#define KK 1024
#define NN 4096
#define NT 32

typedef float f32x16 __attribute__((ext_vector_type(16)));
typedef __bf16 bf16x8 __attribute__((ext_vector_type(8)));
typedef unsigned short u16x8 __attribute__((ext_vector_type(8)));

static __device__ __forceinline__ unsigned short f2bf(float f) {
    unsigned int u = __builtin_bit_cast(unsigned int, f);
    u += 0x7fffu + ((u >> 16) & 1u);   // RNE fp32->bf16 (finite inputs)
    return (unsigned short)(u >> 16);
}
static __device__ __forceinline__ float bf2f(unsigned short s) {
    unsigned int u = ((unsigned int)s) << 16;
    return __builtin_bit_cast(float, u);
}

// ---------------------------------------------------------------------------
// Pack A (x) -> hi/lo bf16, fragment-contiguous: frag (bm,kt,rb,ks) is 64
// lanes x 16B where lane holds A[bm*256+rb*32+(lane&31)][kt*32+ks*16+(lane>>5)*8 ..+8]
// (the v_mfma_f32_32x32x16_bf16 A-operand layout). Linear octet i =
// ((bm*32+kt)*16 + rb*2+ks)*64 + lane.
// ---------------------------------------------------------------------------
__global__ __launch_bounds__(256) void pack_a(const float* __restrict__ x,
        unsigned short* __restrict__ Ah, unsigned short* __restrict__ Al) {
    int i = blockIdx.x * 256 + threadIdx.x;          // [0, 1048576)
    int lane = i & 63, fb = (i >> 6) & 15, kt = (i >> 10) & 31, bm = i >> 15;
    int row = bm * 256 + (fb >> 1) * 32 + (lane & 31);
    int k   = kt * 32 + (fb & 1) * 16 + (lane >> 5) * 8;
    const float4* s = (const float4*)(x + (size_t)row * KK + k);
    float4 a = s[0], b = s[1];
    float v[8] = {a.x, a.y, a.z, a.w, b.x, b.y, b.z, b.w};
    u16x8 h, l;
#pragma unroll
    for (int j = 0; j < 8; ++j) {
        unsigned short hb = f2bf(v[j]);
        h[j] = hb;
        l[j] = f2bf(v[j] - bf2f(hb));                // exact residual, ~8 more bits
    }
    *(u16x8*)(Ah + (size_t)i * 8) = h;
    *(u16x8*)(Al + (size_t)i * 8) = l;
}

// ---------------------------------------------------------------------------
// Pack B (W) -> single array, per (bn,kt) tile: [hi 8KB | lo 8KB], each plane
// 8 frags x 1KB; frag (cb,ks): lane holds B[bn*128+cb*32+(lane&31)][kt*32+
// ks*16+(lane>>5)*8 ..+8]. Staged to LDS linearly by global_load_lds.
// ---------------------------------------------------------------------------
__global__ __launch_bounds__(256) void pack_b(const float* __restrict__ w,
        unsigned short* __restrict__ Bpk) {
    int i = blockIdx.x * 256 + threadIdx.x;          // [0, 524288)
    int lane = i & 63, fb = (i >> 6) & 7, kt = (i >> 9) & 31, bn = i >> 14;
    int col = bn * 128 + (fb >> 1) * 32 + (lane & 31);
    int k   = kt * 32 + (fb & 1) * 16 + (lane >> 5) * 8;
    const float4* s = (const float4*)(w + (size_t)col * KK + k);
    float4 a = s[0], b = s[1];
    float v[8] = {a.x, a.y, a.z, a.w, b.x, b.y, b.z, b.w};
    u16x8 h, l;
#pragma unroll
    for (int j = 0; j < 8; ++j) {
        unsigned short hb = f2bf(v[j]);
        h[j] = hb;
        l[j] = f2bf(v[j] - bf2f(hb));
    }
    size_t tb = ((size_t)bn * 32 + kt) * 8192;
    *(u16x8*)(Bpk + tb + fb * 512 + lane * 8) = h;
    *(u16x8*)(Bpk + tb + 4096 + fb * 512 + lane * 8) = l;
}

static __device__ __forceinline__ void gl16(const unsigned short* g, unsigned short* l) {
    __builtin_amdgcn_global_load_lds(
        (__attribute__((address_space(1))) void*)(void*)g,
        (__attribute__((address_space(3))) void*)(void*)l, 16, 0, 0);
}
static __device__ __forceinline__ void mf(f32x16& d, bf16x8 a, bf16x8 b) {
    d = __builtin_amdgcn_mfma_f32_32x32x16_bf16(a, b, d, 0, 0, 0);
}

// ---------------------------------------------------------------------------
// GEMM: 256x128 wg tile, 4 waves (2Mx2N), per-wave 128x64 = acc[4][2] f32x16.
// BK=32 (2 k-steps of 16). A: global->reg, one tile ahead. B: LDS dbuf 32KB.
// 2 wg/CU -> independent barriers give cross-wg MFMA/memory overlap.
// ---------------------------------------------------------------------------
__global__ __launch_bounds__(256, 2) void qlinear_mfma(
        const unsigned short* __restrict__ Ah, const unsigned short* __restrict__ Al,
        const unsigned short* __restrict__ Bpk,
        const float* __restrict__ bias, float* __restrict__ out) {
    __shared__ __attribute__((aligned(16))) unsigned short sB[2 * 8192];  // 32 KB

    // XCD-bijective swizzle: 1024 wg, XCD x gets 128 contiguous s; chunk covers
    // 8 bm x 16 bn (A 8MB + B 8MB per XCD).
    int bid = blockIdx.x;
    int xc = bid & 7, s = bid >> 3;
    int bm = (xc & 3) * 8 + (s & 7);         // [0,32)
    int bn = (xc >> 2) * 16 + (s >> 3);      // [0,32)

    const int tid = threadIdx.x;
    const int lane = tid & 63, wid = tid >> 6;
    const int wrb = (wid >> 1) * 4;          // A row-block (frag) base
    const int wcb = (wid & 1) * 2;           // B col-block base

    const size_t aoff = (size_t)bm * 262144 + (size_t)wrb * 1024 + lane * 8;
    const size_t bsrc = (size_t)bn * 262144 + tid * 8;
    const unsigned boff = wcb * 1024 + lane * 8;

    f32x16 acc[4][2];
#pragma unroll
    for (int mi = 0; mi < 4; ++mi)
#pragma unroll
        for (int ni = 0; ni < 2; ++ni)
#pragma unroll
            for (int r = 0; r < 16; ++r) acc[mi][ni][r] = 0.f;

    bf16x8 A0h[4], A0l[4], A1h[4], A1l[4];

#define LDA(H, L, T, KS) do { _Pragma("unroll") \
    for (int mi = 0; mi < 4; ++mi) { \
        H[mi] = *(const bf16x8*)(Ah + aoff + (size_t)(T) * 8192 + mi * 1024 + (KS) * 512); \
        L[mi] = *(const bf16x8*)(Al + aoff + (size_t)(T) * 8192 + mi * 1024 + (KS) * 512); \
    } } while (0)
#define STB(T, NB) do { _Pragma("unroll") \
    for (int j = 0; j < 4; ++j) \
        gl16(Bpk + bsrc + (size_t)(T) * 8192 + j * 2048, \
             sB + (NB) * 8192 + j * 2048 + tid * 8); } while (0)

    // prologue
    LDA(A0h, A0l, 0, 0);
    LDA(A1h, A1l, 0, 1);
    STB(0, 0);
    __syncthreads();

    for (int t = 0; t < NT; ++t) {
        const int cur = t & 1, nb = cur ^ 1;
        const unsigned short* sb = sB + cur * 8192;

        bf16x8 B0h[2], B0l[2], B1h[2], B1l[2];
#pragma unroll
        for (int ni = 0; ni < 2; ++ni) {                       // ks0 B frags
            B0h[ni] = *(const bf16x8*)(sb + boff + ni * 1024);
            B0l[ni] = *(const bf16x8*)(sb + 4096 + boff + ni * 1024);
        }
        if (t + 1 < NT) STB(t + 1, nb);                        // stage next B early

        __builtin_amdgcn_s_setprio(1);                         // ks0: 24 MFMA
#pragma unroll
        for (int mi = 0; mi < 4; ++mi)
#pragma unroll
            for (int ni = 0; ni < 2; ++ni) mf(acc[mi][ni], A0h[mi], B0h[ni]);
#pragma unroll
        for (int mi = 0; mi < 4; ++mi)
#pragma unroll
            for (int ni = 0; ni < 2; ++ni) mf(acc[mi][ni], A0l[mi], B0h[ni]);
#pragma unroll
        for (int mi = 0; mi < 4; ++mi)
#pragma unroll
            for (int ni = 0; ni < 2; ++ni) mf(acc[mi][ni], A0h[mi], B0l[ni]);
        __builtin_amdgcn_s_setprio(0);
        __builtin_amdgcn_sched_barrier(0);
        if (t + 1 < NT) LDA(A0h, A0l, t + 1, 0);               // refill ks0 A regs

#pragma unroll
        for (int ni = 0; ni < 2; ++ni) {                       // ks1 B frags
            B1h[ni] = *(const bf16x8*)(sb + boff + ni * 1024 + 512);
            B1l[ni] = *(const bf16x8*)(sb + 4096 + boff + ni * 1024 + 512);
        }
        __builtin_amdgcn_s_setprio(1);                         // ks1: 24 MFMA
#pragma unroll
        for (int mi = 0; mi < 4; ++mi)
#pragma unroll
            for (int ni = 0; ni < 2; ++ni) mf(acc[mi][ni], A1h[mi], B1h[ni]);
#pragma unroll
        for (int mi = 0; mi < 4; ++mi)
#pragma unroll
            for (int ni = 0; ni < 2; ++ni) mf(acc[mi][ni], A1l[mi], B1h[ni]);
#pragma unroll
        for (int mi = 0; mi < 4; ++mi)
#pragma unroll
            for (int ni = 0; ni < 2; ++ni) mf(acc[mi][ni], A1h[mi], B1l[ni]);
        __builtin_amdgcn_s_setprio(0);
        __builtin_amdgcn_sched_barrier(0);
        if (t + 1 < NT) LDA(A1h, A1l, t + 1, 1);               // refill ks1 A regs

        __syncthreads();   // drains vmcnt: B(t+1) staged + A regs landed; ~free
    }
#undef LDA
#undef STB

    // epilogue: 32x32 C/D layout col=lane&31, row=(r&3)+8*(r>>2)+4*(lane>>5)
    const int row0 = bm * 256 + (wid >> 1) * 128 + 4 * (lane >> 5);
    const int col0 = bn * 128 + (wid & 1) * 64 + (lane & 31);
    float bv[2] = {bias[col0], bias[col0 + 32]};
#pragma unroll
    for (int mi = 0; mi < 4; ++mi)
#pragma unroll
        for (int ni = 0; ni < 2; ++ni)
#pragma unroll
            for (int r = 0; r < 16; ++r) {
                int rr = row0 + mi * 32 + (r & 3) + 8 * (r >> 2);
                out[(size_t)rr * NN + col0 + ni * 32] = acc[mi][ni][r] + bv[ni];
            }
}

// ---------------------------------------------------------------------------
// Fallback (ws too small): naive fp32 GEMM.
// ---------------------------------------------------------------------------
__global__ __launch_bounds__(256) void qlinear_naive(const float* __restrict__ x,
                                                     const float* __restrict__ w,
                                                     const float* __restrict__ bias,
                                                     float* __restrict__ out) {
    int n = blockIdx.x * 64 + (threadIdx.x & 63);
    int m = blockIdx.y * 4 + (threadIdx.x >> 6);
    const float4* xr = (const float4*)(x + (size_t)m * KK);
    const float4* wr = (const float4*)(w + (size_t)n * KK);
    float s = 0.f;
    for (int k = 0; k < KK / 4; ++k) {
        float4 a = xr[k], b = wr[k];
        s += a.x * b.x + a.y * b.y + a.z * b.z + a.w * b.w;
    }
    out[(size_t)m * NN + n] = s + bias[n];
}

extern "C" void kernel_launch(void* const* d_in, const int* in_sizes, int n_in,
                              void* d_out, int out_size, void* d_ws, size_t ws_size,
                              hipStream_t stream) {
    (void)in_sizes; (void)n_in; (void)out_size;
    const float* x = (const float*)d_in[0];
    const float* w = (const float*)d_in[1];
    const float* bias = (const float*)d_in[2];
    float* out = (float*)d_out;

    const size_t xcnt = (size_t)MM * KK;   // 8,388,608
    const size_t wcnt = (size_t)NN * KK;   // 4,194,304
    const size_t need = (2 * xcnt + 2 * wcnt) * sizeof(unsigned short);  // 48 MiB

    if (ws_size >= need) {
        unsigned short* Ahp = (unsigned short*)d_ws;
        unsigned short* Alp = Ahp + xcnt;
        unsigned short* Bp  = Alp + xcnt;            // 2*wcnt elems (hi|lo tiled)
        pack_a<<<(int)(xcnt / 8 / 256), 256, 0, stream>>>(x, Ahp, Alp);
        pack_b<<<(int)(wcnt / 8 / 256), 256, 0, stream>>>(w, Bp);
        qlinear_mfma<<<1024, 256, 0, stream>>>(Ahp, Alp, Bp, bias, out);
    } else {
        dim3 grid(NN / 64, MM / 4);
        qlinear_naive<<<grid, 256, 0, stream>>>(x, w, bias, out);
    }
}

// Round 5
// 325.381 us; speedup vs baseline: 1.0584x; 1.0584x over previous
//
#include <hip/hip_runtime.h>
#include <stdint.h>

// out[8192,4096] = x[8192,1024] @ W[4096,1024]^T + bias (all fp32; float_quantize
// exp=8/man=23 is an identity). Split-bf16: hi*hi + lo*hi + hi*lo, fp32 MFMA acc.
// Structure: m201-verified 256x256 8-wave phase template adapted to 3 products:
// per K32 chunk, 6 uniform phases x 16 MFMA, counted vmcnt (never 0 mid-loop).
#define MM 8192
#define KK 1024
#define NN 4096

typedef float f32x4 __attribute__((ext_vector_type(4)));
typedef __bf16 bf16x8 __attribute__((ext_vector_type(8)));
typedef unsigned short u16x8 __attribute__((ext_vector_type(8)));

static __device__ __forceinline__ unsigned short f2bf(float f) {
    unsigned int u = __builtin_bit_cast(unsigned int, f);
    u += 0x7fffu + ((u >> 16) & 1u);    // RNE fp32->bf16 (finite inputs)
    return (unsigned short)(u >> 16);
}
static __device__ __forceinline__ float bf2f(unsigned short s) {
    unsigned int u = ((unsigned int)s) << 16;
    return __builtin_bit_cast(float, u);
}

// ---------------------------------------------------------------------------
// Pack A (x): per (bm,kt) tile of 256 rows x 32 k: [hi plane 8192 | lo plane
// 8192] elems, fragment-contiguous. Frag g in [0,16): lane l holds
// A[bm*256+g*16+(l&15)][kt*32+(l>>4)*8 ..+8] (16x16x32 A-operand layout,
// HW-verified by rounds 1-3 passing). Staged to LDS by linear gl16 copies.
// ---------------------------------------------------------------------------
__global__ __launch_bounds__(256) void pack_a(const float* __restrict__ x,
                                              unsigned short* __restrict__ Apk) {
    int i = blockIdx.x * 256 + threadIdx.x;         // octet id [0, 1048576)
    int lane = i & 63, g = (i >> 6) & 15, kt = (i >> 10) & 31, bm = i >> 15;
    int row = bm * 256 + g * 16 + (lane & 15);
    int k   = kt * 32 + (lane >> 4) * 8;
    const float4* s = (const float4*)(x + (size_t)row * KK + k);
    float4 a = s[0], b = s[1];
    float v[8] = {a.x, a.y, a.z, a.w, b.x, b.y, b.z, b.w};
    u16x8 h, l;
#pragma unroll
    for (int j = 0; j < 8; ++j) {
        unsigned short hb = f2bf(v[j]);
        h[j] = hb;
        l[j] = f2bf(v[j] - bf2f(hb));               // exact residual, ~8 more bits
    }
    size_t tb = (size_t)(bm * 32 + kt) * 16384;
    size_t fo = (size_t)g * 512 + lane * 8;
    *(u16x8*)(Apk + tb + fo) = h;
    *(u16x8*)(Apk + tb + 8192 + fo) = l;
}

// Pack B (W): identical structure over bn in [0,16).
__global__ __launch_bounds__(256) void pack_b(const float* __restrict__ w,
                                              unsigned short* __restrict__ Bpk) {
    int i = blockIdx.x * 256 + threadIdx.x;         // octet id [0, 524288)
    int lane = i & 63, g = (i >> 6) & 15, kt = (i >> 10) & 31, bn = i >> 15;
    int col = bn * 256 + g * 16 + (lane & 15);
    int k   = kt * 32 + (lane >> 4) * 8;
    const float4* s = (const float4*)(w + (size_t)col * KK + k);
    float4 a = s[0], b = s[1];
    float v[8] = {a.x, a.y, a.z, a.w, b.x, b.y, b.z, b.w};
    u16x8 h, l;
#pragma unroll
    for (int j = 0; j < 8; ++j) {
        unsigned short hb = f2bf(v[j]);
        h[j] = hb;
        l[j] = f2bf(v[j] - bf2f(hb));
    }
    size_t tb = (size_t)(bn * 32 + kt) * 16384;
    size_t fo = (size_t)g * 512 + lane * 8;
    *(u16x8*)(Bpk + tb + fo) = h;
    *(u16x8*)(Bpk + tb + 8192 + fo) = l;
}

static __device__ __forceinline__ bf16x8 ldsr(unsigned addr) {
    bf16x8 r;
    asm volatile("ds_read_b128 %0, %1" : "=v"(r) : "v"(addr));
    return r;
}
static __device__ __forceinline__ void gl16(const unsigned short* g, unsigned short* l) {
    __builtin_amdgcn_global_load_lds(
        (__attribute__((address_space(1))) void*)(void*)g,
        (__attribute__((address_space(3))) void*)(void*)l, 16, 0, 0);
}

// ---------------------------------------------------------------------------
// GEMM: 256x256 wg tile, 8 waves (2M x 4N), per-wave 128x64 out = acc[8][4].
// LDS: 2 buf x 4 planes (Ah,Al,Bh,Bl) x 16KB = 128KB. Per K32 chunk: 6 phases
// x 16 MFMA; staging of chunk+1 spread over phases 1-4 (1 plane each);
// derived counted vmcnt at phases 2/4/6.
// ---------------------------------------------------------------------------
__global__ __launch_bounds__(512, 2) void qlinear_mfma(
        const unsigned short* __restrict__ Apk, const unsigned short* __restrict__ Bpk,
        const float* __restrict__ bias, float* __restrict__ out) {
    __shared__ __attribute__((aligned(16))) unsigned short S[2][4][8192];  // 128 KB

    // XCD-bijective swizzle: 512 wg; XCD x owns 4 bm x 16 bn (A panels L2-hot).
    int bid = blockIdx.x;
    int xcd = bid & 7, sq = bid >> 3;
    int bm = xcd * 4 + (sq & 3);          // [0,32)
    int bn = sq >> 2;                     // [0,16)

    const int tid = threadIdx.x;
    const int lane = tid & 63, wid = tid >> 6;
    const int wr2 = wid >> 2;             // M half (0/1)
    const int wc2 = wid & 3;              // N quarter
    const int lr = lane & 15, lg = lane >> 4;

    const unsigned lb = (unsigned)(uintptr_t)(__attribute__((address_space(3))) void*)&S[0][0][0];
    const unsigned fragA = (unsigned)((wr2 * 8) * 1024 + lane * 16);  // byte off in A plane
    const unsigned fragB = (unsigned)((wc2 * 4) * 1024 + lane * 16);  // byte off in B plane

    const size_t abase = (size_t)bm * 524288;   // 32 tiles x 16384 elems
    const size_t bbase = (size_t)bn * 524288;

#define STP(SRCE, BUF, PLN) do {                                   \
        gl16((SRCE) + tid * 8,        &S[BUF][PLN][tid * 8]);      \
        gl16((SRCE) + 4096 + tid * 8, &S[BUF][PLN][4096 + tid * 8]); } while (0)

#define OPEN()                                                     \
    __builtin_amdgcn_s_barrier();                                  \
    asm volatile("s_waitcnt lgkmcnt(0)" ::: "memory");             \
    __builtin_amdgcn_sched_barrier(0);                             \
    __builtin_amdgcn_s_setprio(1)
#define CLOSE()                                                    \
    __builtin_amdgcn_s_setprio(0);                                 \
    __builtin_amdgcn_sched_barrier(0);                             \
    __builtin_amdgcn_s_barrier()
#define CLOSEW(N)                                                  \
    __builtin_amdgcn_s_setprio(0);                                 \
    __builtin_amdgcn_sched_barrier(0);                             \
    asm volatile("s_waitcnt vmcnt(" #N ")" ::: "memory");          \
    __builtin_amdgcn_s_barrier()
#define MF16(AARR, M0, BARR) do { _Pragma("unroll")                \
    for (int mi = 0; mi < 4; ++mi) { _Pragma("unroll")             \
        for (int ni = 0; ni < 4; ++ni)                             \
            acc[(M0) + mi][ni] = __builtin_amdgcn_mfma_f32_16x16x32_bf16( \
                AARR[(M0) + mi], BARR[ni], acc[(M0) + mi][ni], 0, 0, 0);  \
    } } while (0)

    f32x4 acc[8][4];
#pragma unroll
    for (int mi = 0; mi < 8; ++mi)
#pragma unroll
        for (int ni = 0; ni < 4; ++ni) acc[mi][ni] = (f32x4){0.f, 0.f, 0.f, 0.f};

    bf16x8 Ahf[8], Alf[8], Bhf[4], Blf[4];

    // prologue: stage chunk 0, order Ah,Bh,Al,Bl (loads 1-8)
    STP(Apk + abase, 0, 0);
    STP(Bpk + bbase, 0, 2);
    STP(Apk + abase + 8192, 0, 1);
    STP(Bpk + bbase + 8192, 0, 3);
    asm volatile("s_waitcnt vmcnt(4)" ::: "memory");   // Ah,Bh landed
    __builtin_amdgcn_s_barrier();

    for (int ct = 0; ct < 32; ++ct) {
        const int cur = ct & 1, nb = cur ^ 1;
        const unsigned cb = lb + (unsigned)cur * 65536u;
        const unsigned short* nA = Apk + abase + (size_t)(ct + 1) * 16384;
        const unsigned short* nB = Bpk + bbase + (size_t)(ct + 1) * 16384;
        const bool pf = (ct < 31);

        // phase 1: read Ah[0..3]+Bh[0..3]; stage next Ah
#pragma unroll
        for (int mi = 0; mi < 4; ++mi) Ahf[mi] = ldsr(cb + fragA + mi * 1024u);
#pragma unroll
        for (int ni = 0; ni < 4; ++ni) Bhf[ni] = ldsr(cb + 32768u + fragB + ni * 1024u);
        if (pf) STP(nA, nb, 0);
        OPEN(); MF16(Ahf, 0, Bhf); CLOSE();

        // phase 2: read Ah[4..7]; stage next Bh; wait this chunk's Al
#pragma unroll
        for (int mi = 4; mi < 8; ++mi) Ahf[mi] = ldsr(cb + fragA + mi * 1024u);
        if (pf) STP(nB, nb, 2);
        OPEN(); MF16(Ahf, 4, Bhf);
        if (pf) { CLOSEW(6); } else { CLOSEW(2); }

        // phase 3: read Al[0..3]; stage next Al
#pragma unroll
        for (int mi = 0; mi < 4; ++mi) Alf[mi] = ldsr(cb + 16384u + fragA + mi * 1024u);
        if (pf) STP(nA + 8192, nb, 1);
        OPEN(); MF16(Alf, 0, Bhf); CLOSE();

        // phase 4: read Al[4..7]; stage next Bl; wait this chunk's Bl
#pragma unroll
        for (int mi = 4; mi < 8; ++mi) Alf[mi] = ldsr(cb + 16384u + fragA + mi * 1024u);
        if (pf) STP(nB + 8192, nb, 3);
        OPEN(); MF16(Alf, 4, Bhf);
        if (pf) { CLOSEW(8); } else { CLOSEW(0); }

        // phase 5: read Bl[0..3]
#pragma unroll
        for (int ni = 0; ni < 4; ++ni) Blf[ni] = ldsr(cb + 49152u + fragB + ni * 1024u);
        OPEN(); MF16(Ahf, 0, Blf); CLOSE();

        // phase 6: no reads; wait next chunk's Ah+Bh before the close barrier
        OPEN(); MF16(Ahf, 4, Blf);
        if (pf) { CLOSEW(4); } else { CLOSE(); }
    }
#undef STP
#undef OPEN
#undef CLOSE
#undef CLOSEW
#undef MF16

    // epilogue: C/D layout col=lane&15, row=(lane>>4)*4+reg (rounds-1-3-verified)
    const int row0 = bm * 256 + wr2 * 128 + lg * 4;
    const int col0 = bn * 256 + wc2 * 64 + lr;
    float bv[4];
#pragma unroll
    for (int ni = 0; ni < 4; ++ni) bv[ni] = bias[col0 + ni * 16];
#pragma unroll
    for (int mi = 0; mi < 8; ++mi)
#pragma unroll
        for (int ni = 0; ni < 4; ++ni) {
            float* o = out + (size_t)(row0 + mi * 16) * NN + col0 + ni * 16;
#pragma unroll
            for (int r = 0; r < 4; ++r)
                o[(size_t)r * NN] = acc[mi][ni][r] + bv[ni];
        }
}

// ---------------------------------------------------------------------------
// Fallback (ws too small): naive fp32 GEMM.
// ---------------------------------------------------------------------------
__global__ __launch_bounds__(256) void qlinear_naive(const float* __restrict__ x,
                                                     const float* __restrict__ w,
                                                     const float* __restrict__ bias,
                                                     float* __restrict__ out) {
    int n = blockIdx.x * 64 + (threadIdx.x & 63);
    int m = blockIdx.y * 4 + (threadIdx.x >> 6);
    const float4* xr = (const float4*)(x + (size_t)m * KK);
    const float4* wr = (const float4*)(w + (size_t)n * KK);
    float s = 0.f;
    for (int k = 0; k < KK / 4; ++k) {
        float4 a = xr[k], b = wr[k];
        s += a.x * b.x + a.y * b.y + a.z * b.z + a.w * b.w;
    }
    out[(size_t)m * NN + n] = s + bias[n];
}

extern "C" void kernel_launch(void* const* d_in, const int* in_sizes, int n_in,
                              void* d_out, int out_size, void* d_ws, size_t ws_size,
                              hipStream_t stream) {
    (void)in_sizes; (void)n_in; (void)out_size;
    const float* x = (const float*)d_in[0];
    const float* w = (const float*)d_in[1];
    const float* bias = (const float*)d_in[2];
    float* out = (float*)d_out;

    const size_t xcnt = (size_t)MM * KK;   // 8,388,608
    const size_t wcnt = (size_t)NN * KK;   // 4,194,304
    const size_t need = (2 * xcnt + 2 * wcnt) * sizeof(unsigned short);  // ~50 MB

    if (ws_size >= need) {
        unsigned short* Apk = (unsigned short*)d_ws;
        unsigned short* Bpk = Apk + 2 * xcnt;
        pack_a<<<(int)(xcnt / 8 / 256), 256, 0, stream>>>(x, Apk);
        pack_b<<<(int)(wcnt / 8 / 256), 256, 0, stream>>>(w, Bpk);
        qlinear_mfma<<<512, 512, 0, stream>>>(Apk, Bpk, bias, out);
    } else {
        dim3 grid(NN / 64, MM / 4);
        qlinear_naive<<<grid, 256, 0, stream>>>(x, w, bias, out);
    }
}